// Round 7
// baseline (141.941 us; speedup 1.0000x reference)
//
#include <hip/hip_runtime.h>
#include <math.h>

#define NH 16
#define LCACHE 4096

typedef __attribute__((ext_vector_type(8))) short short8;
typedef __attribute__((ext_vector_type(8))) unsigned short ushort8;
typedef __attribute__((ext_vector_type(4))) float f32x4;

__device__ __forceinline__ unsigned short f2bf(float f) {
    unsigned int u = __float_as_uint(f);
    u = (u + 0x7fffu + ((u >> 16) & 1u)) >> 16;   // RNE
    return (unsigned short)u;
}
__device__ __forceinline__ void gload16(const ushort* g, ushort* l) {
    __builtin_amdgcn_global_load_lds((const __attribute__((address_space(1))) void*)g,
                                     (__attribute__((address_space(3))) void*)l, 16, 0, 0);
}

// ---------------------------------------------------------------------------
// K1 prep, block-range specialized (unchanged from round 5, minus out-init):
//  [0,256):   compress conv(s4,k4)+LN -> ck/cv f32 (each row once)
//  [256,768): pack w_attn[:, :1024] / w_proj -> B frags (LDS-staged coalesced)
//  [768,832): pack x -> xp A-frags
//  bid 0 additionally zeroes the 16 producer->consumer flags.
// ---------------------------------------------------------------------------
__global__ __launch_bounds__(256)
void prep_kernel(const float* __restrict__ cached_k, const float* __restrict__ cached_v,
                 const float* __restrict__ kcw, const float* __restrict__ vcw,
                 const float* __restrict__ lkg, const float* __restrict__ lkb,
                 const float* __restrict__ lvg, const float* __restrict__ lvb,
                 const float* __restrict__ x, const float* __restrict__ w_attn,
                 const float* __restrict__ w_proj,
                 float* __restrict__ ck, float* __restrict__ cv,
                 ushort* __restrict__ xp, ushort* __restrict__ wq,
                 ushort* __restrict__ wp, int* __restrict__ flags)
{
    __shared__ float Wt[64][65];
    const int bid = blockIdx.x, tid = threadIdx.x;
    const int w = tid >> 6, l = tid & 63;

    if (bid == 0 && tid < 16) flags[tid] = 0;

    if (bid < 256) {
        // ---- compress ----
        const int bh = bid >> 1, T = bid & 1;
        const float* S = (T ? cached_v : cached_k) + (size_t)bh * (LCACHE * 64);
        const float* cwp = T ? vcw : kcw;
        float4 w4 = *(const float4*)(cwp + l * 4);
        float g = (T ? lvg : lkg)[l], bb = (T ? lvb : lkb)[l];
        float* dst = (T ? cv : ck) + (size_t)bh * 4096;
#pragma unroll
        for (int it = 0; it < 4; ++it) {
            float av[4];
#pragma unroll
            for (int q = 0; q < 4; ++q) {
                int lc = w * 16 + it * 4 + q;
                const float* p = S + (size_t)lc * 256 + l;
                float acc = p[0] * w4.x;
                acc = fmaf(p[64],  w4.y, acc);
                acc = fmaf(p[128], w4.z, acc);
                acc = fmaf(p[192], w4.w, acc);
                av[q] = acc;
            }
            float s1[4], s2[4];
#pragma unroll
            for (int q = 0; q < 4; ++q) { s1[q] = av[q]; s2[q] = av[q] * av[q]; }
#pragma unroll
            for (int o = 32; o; o >>= 1) {
#pragma unroll
                for (int q = 0; q < 4; ++q) {
                    s1[q] += __shfl_xor(s1[q], o);
                    s2[q] += __shfl_xor(s2[q], o);
                }
            }
#pragma unroll
            for (int q = 0; q < 4; ++q) {
                int lc = w * 16 + it * 4 + q;
                float mu  = s1[q] * 0.015625f;
                float var = s2[q] * 0.015625f - mu * mu;
                dst[(size_t)lc * 64 + l] = (av[q] - mu) * rsqrtf(var + 1e-5f) * g + bb;
            }
        }
        return;
    }

    if (bid < 768) {
        // ---- W pack via LDS staging ----
        const int isP = (bid >= 512);
        const int g2  = bid - (isP ? 512 : 256);
        const int nt = g2 >> 4, kt = g2 & 15;
        const float* W = isP ? w_proj : w_attn;
        const int ldw  = isP ? 1024 : 3072;
        ushort* D      = isP ? wp : wq;
#pragma unroll
        for (int rep = 0; rep < 16; ++rep) {
            int lin = rep * 256 + tid;
            int kr = lin >> 6, nn = lin & 63;
            Wt[kr][nn] = W[(size_t)(kt * 64 + kr) * ldw + nt * 64 + nn];
        }
        __syncthreads();
        int r = l & 15, kg8 = l >> 4;
#pragma unroll
        for (int e = 0; e < 2; ++e) {
            int bi = w + e * 4;
            int kb = bi >> 2, nb = bi & 3;
            ushort8 o;
#pragma unroll
            for (int j = 0; j < 8; ++j)
                o[j] = f2bf(Wt[kb * 32 + kg8 * 8 + j][nb * 16 + r]);
            size_t f_lin = (size_t)(nt * 16 + kt) * 8 + bi;
            *(ushort8*)(D + f_lin * 512 + l * 8) = o;
        }
        return;
    }

    // ---- x pack ----
    {
        int bid2 = bid - 768;
        int r = l & 15, kg8 = l >> 4;
#pragma unroll
        for (int i = 0; i < 4; ++i) {
            int f = bid2 * 16 + w * 4 + i;
            int mt = f >> 6, kt = (f >> 2) & 15, fi = f & 3;
            int kb = fi >> 1, mb = fi & 1;
            int m  = mt * 32 + mb * 16 + r;
            int k0 = kt * 64 + kb * 32 + kg8 * 8;
            const float* s = x + (size_t)m * 1024 + k0;
            ushort8 o;
#pragma unroll
            for (int j = 0; j < 8; ++j) o[j] = f2bf(s[j]);
            *(ushort8*)(xp + (size_t)f * 512 + l * 8) = o;
        }
    }
}

// ---------------------------------------------------------------------------
// K2 fused producer/consumer, 512 blocks x 512 thr, ALL co-resident
// (launch_bounds(512,4) => <=128 VGPR => 2 blocks/CU; LDS 64KB => 2/CU).
//  bid [0,256)  producer (b,h,half): reg-direct q-GEMM (barrier-free, wave
//               owns (mb,nb), full K) + causal attn + yp write -> fence ->
//               flags[mtA]++.
//  bid [256,512) consumer (mt,nt): prefetch wp kt0..7 into LDS (survives the
//               acquire invalidate), spin flags[mt]==16, fence, reg-direct
//               out-GEMM (B kt8..15 from L2), store out + b_proj (exclusive
//               tile, no atomics).
// ---------------------------------------------------------------------------
__global__ __launch_bounds__(512, 4)
void fused2_kernel(const float* __restrict__ ck, const float* __restrict__ cv,
                   const float* __restrict__ b_attn, const float* __restrict__ b_proj,
                   const ushort* __restrict__ xp, const ushort* __restrict__ wq,
                   const ushort* __restrict__ wp, ushort* __restrict__ yp,
                   int* __restrict__ flags, float* __restrict__ out)
{
    __shared__ __align__(16) char smem[65536];
    const int bid = blockIdx.x, tid = threadIdx.x;
    const int w = tid >> 6, l = tid & 63;
    const int c = l & 15, rg = l >> 4;
    const int mb = w >> 2, nb = w & 3;

    if (bid < 256) {
        // ================= producer =================
        float (*ck_s)[65] = (float(*)[65])smem;                // 16640 B
        float (*cv_s)[65] = (float(*)[65])(smem + 16640);      // 16640 B
        float (*qs)[68]   = (float(*)[68])(smem + 33280);      //  8704 B

        const int h = ((bid & 7) << 1) | ((bid >> 3) & 1);     // same h -> same XCD
        const int rem = bid >> 4, b = rem >> 1, half = rem & 1;
        const int mtA = b * 2 + half;

        // ck/cv prefetch (lands under the GEMM)
        const float4* ckg = (const float4*)(ck + (size_t)(b * NH + h) * 4096);
        const float4* cvg = (const float4*)(cv + (size_t)(b * NH + h) * 4096);
        float4 rk0 = ckg[tid], rk1 = ckg[tid + 512];
        float4 rv0 = cvg[tid], rv1 = cvg[tid + 512];

        // barrier-free q-GEMM: wave owns (mb,nb), full K=1024
        const ushort* ab  = xp + (size_t)mtA * 32768 + mb * 512;
        const ushort* bbq = wq + (size_t)h * 65536 + nb * 512;
        f32x4 qa = {0.f, 0.f, 0.f, 0.f};
#pragma unroll
        for (int kt = 0; kt < 16; ++kt) {
            const ushort* A = ab + kt * 2048;
            const ushort* B = bbq + kt * 4096;
            short8 a0 = *(const short8*)(A + l * 8);
            short8 a1 = *(const short8*)(A + 1024 + l * 8);
            short8 b0 = *(const short8*)(B + l * 8);
            short8 b1 = *(const short8*)(B + 2048 + l * 8);
            qa = __builtin_amdgcn_mfma_f32_16x16x32_bf16(a0, b0, qa, 0, 0, 0);
            qa = __builtin_amdgcn_mfma_f32_16x16x32_bf16(a1, b1, qa, 0, 0, 0);
        }

        // ck/cv regs -> LDS
        {
            int row = tid >> 4, col = (tid & 15) * 4;
            ck_s[row][col] = rk0.x; ck_s[row][col+1] = rk0.y;
            ck_s[row][col+2] = rk0.z; ck_s[row][col+3] = rk0.w;
            ck_s[row+32][col] = rk1.x; ck_s[row+32][col+1] = rk1.y;
            ck_s[row+32][col+2] = rk1.z; ck_s[row+32][col+3] = rk1.w;
            cv_s[row][col] = rv0.x; cv_s[row][col+1] = rv0.y;
            cv_s[row][col+2] = rv0.z; cv_s[row][col+3] = rv0.w;
            cv_s[row+32][col] = rv1.x; cv_s[row+32][col+1] = rv1.y;
            cv_s[row+32][col+2] = rv1.z; cv_s[row+32][col+3] = rv1.w;
        }
        // q + bias, softmax scale -> qs  (C/D: row = rg*4+rr, col = c)
        {
            float bv = b_attn[h * 64 + nb * 16 + c];
#pragma unroll
            for (int rr = 0; rr < 4; ++rr)
                qs[mb * 16 + rg * 4 + rr][nb * 16 + c] = (qa[rr] + bv) * 0.125f;
        }
        __syncthreads();

        // causal attention, 4 query rows per wave; yp write (packed-A layout)
#pragma unroll
        for (int rr = 0; rr < 4; ++rr) {
            const int i  = w * 4 + rr;
            const int gq = half * 32 + i;
            float s = 0.f;
#pragma unroll
            for (int d = 0; d < 64; ++d)
                s = fmaf(qs[i][d], ck_s[l][d], s);
            bool valid = (l <= gq);
            s = valid ? s : -3.0e38f;
            float mx = s;
#pragma unroll
            for (int o = 32; o; o >>= 1) mx = fmaxf(mx, __shfl_xor(mx, o));
            float e = valid ? __expf(s - mx) : 0.f;
            float sum = e;
#pragma unroll
            for (int o = 32; o; o >>= 1) sum += __shfl_xor(sum, o);
            float p = e / sum;

            float a0 = 0.f, a1 = 0.f, a2 = 0.f, a3 = 0.f;
#pragma unroll
            for (int j = 0; j < 64; j += 4) {
                a0 = fmaf(__shfl(p, j + 0), cv_s[j + 0][l], a0);
                a1 = fmaf(__shfl(p, j + 1), cv_s[j + 1][l], a1);
                a2 = fmaf(__shfl(p, j + 2), cv_s[j + 2][l], a2);
                a3 = fmaf(__shfl(p, j + 3), cv_s[j + 3][l], a3);
            }
            float acc = (a0 + a1) + (a2 + a3);

            int mb2 = i >> 4, r15 = i & 15;
            int kb  = l >> 5, ke = l & 31;
            int l2  = ((ke >> 3) << 4) | r15;
            int j2  = ke & 7;
            size_t off = (size_t)mtA * 32768 + (size_t)h * 2048
                       + (size_t)(kb * 2 + mb2) * 512 + (size_t)l2 * 8 + j2;
            yp[off] = f2bf(acc);
        }

        // release: writes visible device-wide, then signal
        __threadfence();
        __syncthreads();
        if (tid == 0) atomicAdd(&flags[mtA], 1);
    } else {
        // ================= consumer =================
        ushort* bl = (ushort*)smem;                            // 64 KiB B cache
        const int cid = bid - 256;
        const int nt = ((cid & 7) << 1) | ((cid >> 3) & 1);    // same nt -> same XCD
        const int mt = cid >> 4;
        const ushort* wpb = wp + (size_t)nt * 65536;

        // prefetch B frags kt0..7 into LDS (immune to the acquire invalidate)
#pragma unroll
        for (int s2 = 0; s2 < 8; ++s2) {
            int f2 = s2 * 8 + w;
            gload16(wpb + (size_t)f2 * 512 + l * 8, bl + f2 * 512);
        }

        // spin until all 16 heads of mt have produced (1 poller/block, bounded)
        if (tid == 0) {
            int guard = 0;
            while (atomicAdd(&flags[mt], 0) < 16) {
                __builtin_amdgcn_s_sleep(8);
                if (++guard > (1 << 21)) break;   // fail visibly, never hang
            }
        }
        __syncthreads();
        __threadfence();                                       // acquire
        asm volatile("s_waitcnt vmcnt(0)" ::: "memory");       // LDS prefetch landed
        __syncthreads();

        // barrier-free out-GEMM: wave owns (mb,nb), full K=1024
        const ushort* aby = yp + (size_t)mt * 32768 + mb * 512;
        f32x4 oa = {0.f, 0.f, 0.f, 0.f};
#pragma unroll
        for (int kt = 0; kt < 16; ++kt) {
            const ushort* A = aby + kt * 2048;
            short8 a0 = *(const short8*)(A + l * 8);
            short8 a1 = *(const short8*)(A + 1024 + l * 8);
            short8 b0, b1;
            if (kt < 8) {
                b0 = *(const short8*)(bl + (kt * 8 + nb) * 512 + l * 8);
                b1 = *(const short8*)(bl + (kt * 8 + 4 + nb) * 512 + l * 8);
            } else {
                const ushort* B = wpb + (size_t)kt * 4096 + nb * 512;
                b0 = *(const short8*)(B + l * 8);
                b1 = *(const short8*)(B + 2048 + l * 8);
            }
            oa = __builtin_amdgcn_mfma_f32_16x16x32_bf16(a0, b0, oa, 0, 0, 0);
            oa = __builtin_amdgcn_mfma_f32_16x16x32_bf16(a1, b1, oa, 0, 0, 0);
        }
#pragma unroll
        for (int rr = 0; rr < 4; ++rr) {
            int m = mt * 32 + mb * 16 + rg * 4 + rr;
            int n = nt * 64 + nb * 16 + c;
            out[(size_t)m * 1024 + n] = oa[rr] + b_proj[n];
        }
    }
}

// ---------------------------------------------------------------------------
extern "C" void kernel_launch(void* const* d_in, const int* in_sizes, int n_in,
                              void* d_out, int out_size, void* d_ws, size_t ws_size,
                              hipStream_t stream)
{
    const float* x        = (const float*)d_in[0];
    const float* cached_k = (const float*)d_in[1];
    const float* cached_v = (const float*)d_in[2];
    const float* w_attn   = (const float*)d_in[3];
    const float* b_attn   = (const float*)d_in[4];
    const float* w_proj   = (const float*)d_in[5];
    const float* b_proj   = (const float*)d_in[6];
    const float* k_conv   = (const float*)d_in[7];
    const float* v_conv   = (const float*)d_in[8];
    const float* ln_k_g   = (const float*)d_in[9];
    const float* ln_k_b   = (const float*)d_in[10];
    const float* ln_v_g   = (const float*)d_in[11];
    const float* ln_v_b   = (const float*)d_in[12];

    ushort* xp = (ushort*)d_ws;            // 524288 u16
    ushort* wq = xp + 524288;              // 1048576 u16
    ushort* wp = wq + 1048576;             // 1048576 u16
    ushort* yp = wp + 1048576;             // 524288 u16
    float*  ck = (float*)(yp + 524288);    // 524288 f32
    float*  cv = ck + 524288;              // 524288 f32
    int* flags = (int*)(cv + 524288);      // 16 int
    float* out = (float*)d_out;

    prep_kernel<<<832, 256, 0, stream>>>(cached_k, cached_v, k_conv, v_conv,
                                         ln_k_g, ln_k_b, ln_v_g, ln_v_b,
                                         x, w_attn, w_proj, ck, cv, xp, wq, wp, flags);
    fused2_kernel<<<512, 512, 0, stream>>>(ck, cv, b_attn, b_proj,
                                           xp, wq, wp, yp, flags, out);
}

// Round 8
// 28.234 us; speedup vs baseline: 5.0273x; 5.0273x over previous
//
#include <hip/hip_runtime.h>
#include <math.h>

#define NH 16
#define LCACHE 4096

typedef __attribute__((ext_vector_type(8))) short short8;
typedef __attribute__((ext_vector_type(8))) unsigned short ushort8;
typedef __attribute__((ext_vector_type(4))) float f32x4;

__device__ __forceinline__ unsigned short f2bf(float f) {
    unsigned int u = __float_as_uint(f);
    u = (u + 0x7fffu + ((u >> 16) & 1u)) >> 16;   // RNE
    return (unsigned short)u;
}
__device__ __forceinline__ void gload16(const ushort* g, ushort* l) {
    __builtin_amdgcn_global_load_lds((const __attribute__((address_space(1))) void*)g,
                                     (__attribute__((address_space(3))) void*)l, 16, 0, 0);
}
// stage one K-tile (A 4 frags + B 8 frags) into 4-buffer ring
__device__ __forceinline__ void stage6(const ushort* agb, const ushort* bgb,
                                       ushort* stgb, int buf, int kt, int w4, int l)
{
    const ushort* ga = agb + (size_t)kt * 2048 + w4 * 512 + l * 8;
    const ushort* gb = bgb + (size_t)kt * 4096 + w4 * 1024 + l * 8;
    ushort* la = stgb + buf * 6144 + w4 * 512;
    ushort* lb = stgb + buf * 6144 + 2048 + w4 * 1024;
    gload16(ga, la); gload16(gb, lb); gload16(gb + 512, lb + 512);
}

// ---------------------------------------------------------------------------
// K1 prep: 512 blocks x 256 thr, every block does:
//   wpack unit (bid): stage-to-reg first (overlaps compress), LDS transpose,
//                     emit 8 B-frags of w_attn[:, :1024] (bid<256) or w_proj.
//   compress unit: bh=bid>>2, T=(bid>>1)&1, half=bid&1 -> 32 rows conv+LN,
//                  stored DIRECTLY as bf16 MFMA A-frags:
//                  ck:  A[m=key,k=d];  cv: transposed A[m=d,k=key].
//   xpack (bid<64): x -> A-frags.
// ---------------------------------------------------------------------------
__global__ __launch_bounds__(256)
void prep_kernel(const float* __restrict__ cached_k, const float* __restrict__ cached_v,
                 const float* __restrict__ kcw, const float* __restrict__ vcw,
                 const float* __restrict__ lkg, const float* __restrict__ lkb,
                 const float* __restrict__ lvg, const float* __restrict__ lvb,
                 const float* __restrict__ x, const float* __restrict__ w_attn,
                 const float* __restrict__ w_proj,
                 ushort* __restrict__ ckf, ushort* __restrict__ cvtf,
                 ushort* __restrict__ xp, ushort* __restrict__ wq,
                 ushort* __restrict__ wp)
{
    __shared__ float Wt[64][65];
    const int bid = blockIdx.x, tid = threadIdx.x;
    const int w = tid >> 6, l = tid & 63;

    // ---- wpack staging loads into regs (issued early, land under compress)
    const int isP = (bid >= 256);
    const int g2  = bid & 255;
    const int ntw = g2 >> 4, ktw = g2 & 15;
    const float* W = isP ? w_proj : w_attn;
    const int ldw  = isP ? 1024 : 3072;
    ushort* D      = isP ? wp : wq;
    float wreg[16];
#pragma unroll
    for (int rep = 0; rep < 16; ++rep) {
        int lin = rep * 256 + tid;
        int kr = lin >> 6, nn = lin & 63;
        wreg[rep] = W[(size_t)(ktw * 64 + kr) * ldw + ntw * 64 + nn];
    }

    // ---- compress 32 rows -> bf16 frag scatter ----
    {
        const int bh = bid >> 2, sub = bid & 3;
        const int T = sub >> 1, half = sub & 1;
        const float* S = (T ? cached_v : cached_k) + (size_t)bh * (LCACHE * 64);
        const float* cwp = T ? vcw : kcw;
        float4 w4v = *(const float4*)(cwp + l * 4);
        float g = (T ? lvg : lkg)[l], bb = (T ? lvb : lkb)[l];
        ushort* dstf = (T ? cvtf : ckf) + (size_t)bh * 4096;
#pragma unroll
        for (int it = 0; it < 2; ++it) {
            float av[4];
#pragma unroll
            for (int q = 0; q < 4; ++q) {
                int key = half * 32 + w * 8 + it * 4 + q;
                const float* p = S + (size_t)key * 256 + l;
                float acc = p[0] * w4v.x;
                acc = fmaf(p[64],  w4v.y, acc);
                acc = fmaf(p[128], w4v.z, acc);
                acc = fmaf(p[192], w4v.w, acc);
                av[q] = acc;
            }
            float s1[4], s2[4];
#pragma unroll
            for (int q = 0; q < 4; ++q) { s1[q] = av[q]; s2[q] = av[q] * av[q]; }
#pragma unroll
            for (int o = 32; o; o >>= 1) {
#pragma unroll
                for (int q = 0; q < 4; ++q) {
                    s1[q] += __shfl_xor(s1[q], o);
                    s2[q] += __shfl_xor(s2[q], o);
                }
            }
#pragma unroll
            for (int q = 0; q < 4; ++q) {
                int key = half * 32 + w * 8 + it * 4 + q;
                float mu  = s1[q] * 0.015625f;
                float var = s2[q] * 0.015625f - mu * mu;
                float outv = (av[q] - mu) * rsqrtf(var + 1e-5f) * g + bb;
                const int d = l;
                int off;
                if (T) // cv^T frag: (m=d, k=key)
                    off = ((d >> 4) * 2 + (key >> 5)) * 512
                        + ((key >> 3) & 3) * 128 + (d & 15) * 8 + (key & 7);
                else   // ck frag: (m=key, k=d)
                    off = ((key >> 4) * 2 + (d >> 5)) * 512
                        + ((d >> 3) & 3) * 128 + (key & 15) * 8 + (d & 7);
                dstf[off] = f2bf(outv);
            }
        }
    }

    // ---- wpack: regs -> LDS, transpose-pack 8 frags ----
    {
#pragma unroll
        for (int rep = 0; rep < 16; ++rep) {
            int lin = rep * 256 + tid;
            Wt[lin >> 6][lin & 63] = wreg[rep];
        }
        __syncthreads();
        int r = l & 15, kg8 = l >> 4;
#pragma unroll
        for (int e = 0; e < 2; ++e) {
            int bi = w + e * 4;
            int kb = bi >> 2, nb = bi & 3;
            ushort8 o;
#pragma unroll
            for (int j = 0; j < 8; ++j)
                o[j] = f2bf(Wt[kb * 32 + kg8 * 8 + j][nb * 16 + r]);
            size_t f_lin = (size_t)(ntw * 16 + ktw) * 8 + bi;
            *(ushort8*)(D + f_lin * 512 + l * 8) = o;
        }
    }

    // ---- xpack ----
    if (bid < 64) {
        int r = l & 15, kg8 = l >> 4;
#pragma unroll
        for (int i = 0; i < 4; ++i) {
            int f = bid * 16 + w * 4 + i;
            int mt = f >> 6, kt = (f >> 2) & 15, fi = f & 3;
            int kb = fi >> 1, mb = fi & 1;
            int m  = mt * 32 + mb * 16 + r;
            int k0 = kt * 64 + kb * 32 + kg8 * 8;
            const float* s = x + (size_t)m * 1024 + k0;
            ushort8 o;
#pragma unroll
            for (int j = 0; j < 8; ++j) o[j] = f2bf(s[j]);
            *(ushort8*)(xp + (size_t)f * 512 + l * 8) = o;
        }
    }
}

// ---------------------------------------------------------------------------
// K2: per (b,h,half).  q-GEMM 32x64 (split-K, 4-buf depth-3 counted-vmcnt) |
// MFMA attention: S^T = mfma(ck, q) -> in-reg softmax (2 shfl_xor) ->
// P_lds (bf16, XOR-swizzled) -> O^T = mfma(cv^T, P) | yp frag scatter.
// ---------------------------------------------------------------------------
__global__ __launch_bounds__(512)
void attn_kernel(const ushort* __restrict__ ckf, const ushort* __restrict__ cvtf,
                 const float* __restrict__ b_attn,
                 const ushort* __restrict__ xp, const ushort* __restrict__ wq,
                 ushort* __restrict__ yp)
{
    __shared__ __align__(16) ushort stg[2][4][6144];   // 98304 B
    __shared__ __align__(16) float qs[32][68];
    __shared__ __align__(16) ushort P_lds[32 * 64];

    const int bid = blockIdx.x;
    const int h    = ((bid & 7) << 1) | ((bid >> 3) & 1);   // same h -> same XCD
    const int rem  = bid >> 4;
    const int b    = rem >> 1;
    const int half = rem & 1;
    const int mtA  = b * 2 + half;

    const int tid = threadIdx.x;
    const int w = tid >> 6, l = tid & 63;
    const int kg = w >> 2, w4 = w & 3;
    const int c = l & 15, rg = l >> 4;

    const ushort* agb = xp + (size_t)mtA * 32768;
    const ushort* bgb = wq + (size_t)h * 65536;
    ushort* stgb = &stg[kg][0][0];
    stage6(agb, bgb, stgb, 0, kg * 8 + 0, w4, l);
    stage6(agb, bgb, stgb, 1, kg * 8 + 1, w4, l);
    stage6(agb, bgb, stgb, 2, kg * 8 + 2, w4, l);

    f32x4 acc0 = {0.f,0.f,0.f,0.f}, acc1 = {0.f,0.f,0.f,0.f};
#pragma unroll
    for (int s = 0; s < 8; ++s) {
        if (s < 6)       asm volatile("s_waitcnt vmcnt(6)" ::: "memory");
        else if (s == 6) asm volatile("s_waitcnt vmcnt(3)" ::: "memory");
        else             asm volatile("s_waitcnt vmcnt(0)" ::: "memory");
        __builtin_amdgcn_s_barrier();
        if (s < 5) stage6(agb, bgb, stgb, (s + 3) & 3, kg * 8 + s + 3, w4, l);
        const ushort* La = stgb + (s & 3) * 6144;
        const ushort* Lb = La + 2048;
        short8 b0  = *(const short8*)(Lb + (size_t)w4 * 512 + l * 8);
        short8 a00 = *(const short8*)(La + (size_t)l * 8);
        short8 a01 = *(const short8*)(La + 512 + (size_t)l * 8);
        acc0 = __builtin_amdgcn_mfma_f32_16x16x32_bf16(a00, b0, acc0, 0, 0, 0);
        acc1 = __builtin_amdgcn_mfma_f32_16x16x32_bf16(a01, b0, acc1, 0, 0, 0);
        short8 b1  = *(const short8*)(Lb + (size_t)(4 + w4) * 512 + l * 8);
        short8 a10 = *(const short8*)(La + 1024 + (size_t)l * 8);
        short8 a11 = *(const short8*)(La + 1536 + (size_t)l * 8);
        acc0 = __builtin_amdgcn_mfma_f32_16x16x32_bf16(a10, b1, acc0, 0, 0, 0);
        acc1 = __builtin_amdgcn_mfma_f32_16x16x32_bf16(a11, b1, acc1, 0, 0, 0);
    }

    // split-K reduce -> qs (group1 adds bias + softmax scale)
    {
        const int n = w4 * 16 + c;
        if (kg == 0) {
#pragma unroll
            for (int mb = 0; mb < 2; ++mb) {
                f32x4 acc = mb ? acc1 : acc0;
#pragma unroll
                for (int rr = 0; rr < 4; ++rr)
                    qs[mb * 16 + rg * 4 + rr][n] = acc[rr];
            }
        }
        __syncthreads();
        if (kg == 1) {
            float bv = b_attn[h * 64 + n];
#pragma unroll
            for (int mb = 0; mb < 2; ++mb) {
                f32x4 acc = mb ? acc1 : acc0;
#pragma unroll
                for (int rr = 0; rr < 4; ++rr) {
                    int m = mb * 16 + rg * 4 + rr;
                    qs[m][n] = (qs[m][n] + acc[rr] + bv) * 0.125f;
                }
            }
        }
        __syncthreads();
    }

    // ===== MFMA attention =====
    const int g = w & 1, dup = w >> 1;
    const ushort* ckb = ckf + (size_t)(b * NH + h) * 4096;
    const ushort* cvb = cvtf + (size_t)(b * NH + h) * 4096;

    short8 akf[4][2];
#pragma unroll
    for (int mf = 0; mf < 4; ++mf)
#pragma unroll
        for (int kf = 0; kf < 2; ++kf)
            akf[mf][kf] = *(const short8*)(ckb + (mf * 2 + kf) * 512 + l * 8);

    short8 qb[2];
#pragma unroll
    for (int kf = 0; kf < 2; ++kf) {
        int row = 16 * g + c;
        int d0  = 32 * kf + 8 * rg;
        float4 v0 = *(const float4*)&qs[row][d0];
        float4 v1 = *(const float4*)&qs[row][d0 + 4];
        ushort8 t;
        t[0] = f2bf(v0.x); t[1] = f2bf(v0.y); t[2] = f2bf(v0.z); t[3] = f2bf(v0.w);
        t[4] = f2bf(v1.x); t[5] = f2bf(v1.y); t[6] = f2bf(v1.z); t[7] = f2bf(v1.w);
        qb[kf] = (short8)t;
    }

    f32x4 sacc[4];
#pragma unroll
    for (int mf = 0; mf < 4; ++mf) { sacc[mf][0]=0.f; sacc[mf][1]=0.f; sacc[mf][2]=0.f; sacc[mf][3]=0.f; }
#pragma unroll
    for (int mf = 0; mf < 4; ++mf) {
        sacc[mf] = __builtin_amdgcn_mfma_f32_16x16x32_bf16(akf[mf][0], qb[0], sacc[mf], 0, 0, 0);
        sacc[mf] = __builtin_amdgcn_mfma_f32_16x16x32_bf16(akf[mf][1], qb[1], sacc[mf], 0, 0, 0);
    }

    // softmax: lane holds 16 key-scores for query gq
    const int gq = half * 32 + 16 * g + c;
    float pv[4][4];
    float mx = -3.0e38f;
#pragma unroll
    for (int mf = 0; mf < 4; ++mf)
#pragma unroll
        for (int rr = 0; rr < 4; ++rr) {
            int kidx = 16 * mf + 4 * rg + rr;
            float sc = (kidx <= gq) ? sacc[mf][rr] : -3.0e38f;
            pv[mf][rr] = sc;
            mx = fmaxf(mx, sc);
        }
    mx = fmaxf(mx, __shfl_xor(mx, 16));
    mx = fmaxf(mx, __shfl_xor(mx, 32));
    float sum = 0.f;
#pragma unroll
    for (int mf = 0; mf < 4; ++mf)
#pragma unroll
        for (int rr = 0; rr < 4; ++rr) {
            int kidx = 16 * mf + 4 * rg + rr;
            float e = (kidx <= gq) ? __expf(pv[mf][rr] - mx) : 0.f;
            pv[mf][rr] = e;
            sum += e;
        }
    sum += __shfl_xor(sum, 16);
    sum += __shfl_xor(sum, 32);
    float inv = 1.0f / sum;

    if (dup == 0) {
        int q = 16 * g + c;
        int swz = (q & 7) << 3;
#pragma unroll
        for (int mf = 0; mf < 4; ++mf)
#pragma unroll
            for (int rr = 0; rr < 4; ++rr) {
                int kidx = 16 * mf + 4 * rg + rr;
                P_lds[q * 64 + (kidx ^ swz)] = f2bf(pv[mf][rr] * inv);
            }
    }
    __syncthreads();

    // PV: O^T = mfma(cv^T, P)
    short8 avf[2], pb[2];
#pragma unroll
    for (int kf = 0; kf < 2; ++kf) {
        avf[kf] = *(const short8*)(cvb + (dup * 2 + kf) * 512 + l * 8);
        int q = 16 * g + c;
        int key0 = 32 * kf + 8 * rg;
        pb[kf] = *(const short8*)&P_lds[q * 64 + (key0 ^ ((q & 7) << 3))];
    }
    f32x4 oacc = {0.f, 0.f, 0.f, 0.f};
    oacc = __builtin_amdgcn_mfma_f32_16x16x32_bf16(avf[0], pb[0], oacc, 0, 0, 0);
    oacc = __builtin_amdgcn_mfma_f32_16x16x32_bf16(avf[1], pb[1], oacc, 0, 0, 0);

    // yp scatter: row i = 16g + c, col d = 16*dup + 4*rg + rr (within head h)
#pragma unroll
    for (int rr = 0; rr < 4; ++rr) {
        int d  = 16 * dup + 4 * rg + rr;
        int kb = d >> 5, ke = d & 31;
        int l2 = ((ke >> 3) << 4) | c;
        int j2 = ke & 7;
        size_t off = (size_t)mtA * 32768 + (size_t)h * 2048
                   + (size_t)(kb * 2 + g) * 512 + (size_t)l2 * 8 + j2;
        yp[off] = f2bf(oacc[rr]);
    }
}

// ---------------------------------------------------------------------------
// K3: out = y @ w_proj + b_proj.  32x64 tile, split-K over 8 waves,
// 4-buf depth-3 counted-vmcnt pipeline, LDS reduce.  XCD-swizzled nt.
// ---------------------------------------------------------------------------
__global__ __launch_bounds__(512)
void gemm2_kernel(const ushort* __restrict__ Ap, const ushort* __restrict__ Bp,
                  const float* __restrict__ bias, float* __restrict__ C)
{
    __shared__ __align__(16) ushort stg[2][4][6144];
    __shared__ float red[32][68];

    const int bid = blockIdx.x;
    const int nt = ((bid & 7) << 1) | ((bid >> 3) & 1);
    const int mt = bid >> 4;
    const int tid = threadIdx.x;
    const int w = tid >> 6, l = tid & 63;
    const int kg = w >> 2, w4 = w & 3;

    const ushort* agb = Ap + (size_t)mt * 32768;
    const ushort* bgb = Bp + (size_t)nt * 65536;
    ushort* stgb = &stg[kg][0][0];
    stage6(agb, bgb, stgb, 0, kg * 8 + 0, w4, l);
    stage6(agb, bgb, stgb, 1, kg * 8 + 1, w4, l);
    stage6(agb, bgb, stgb, 2, kg * 8 + 2, w4, l);

    f32x4 acc0 = {0.f,0.f,0.f,0.f}, acc1 = {0.f,0.f,0.f,0.f};
#pragma unroll
    for (int s = 0; s < 8; ++s) {
        if (s < 6)       asm volatile("s_waitcnt vmcnt(6)" ::: "memory");
        else if (s == 6) asm volatile("s_waitcnt vmcnt(3)" ::: "memory");
        else             asm volatile("s_waitcnt vmcnt(0)" ::: "memory");
        __builtin_amdgcn_s_barrier();
        if (s < 5) stage6(agb, bgb, stgb, (s + 3) & 3, kg * 8 + s + 3, w4, l);
        const ushort* La = stgb + (s & 3) * 6144;
        const ushort* Lb = La + 2048;
        short8 b0  = *(const short8*)(Lb + (size_t)w4 * 512 + l * 8);
        short8 a00 = *(const short8*)(La + (size_t)l * 8);
        short8 a01 = *(const short8*)(La + 512 + (size_t)l * 8);
        acc0 = __builtin_amdgcn_mfma_f32_16x16x32_bf16(a00, b0, acc0, 0, 0, 0);
        acc1 = __builtin_amdgcn_mfma_f32_16x16x32_bf16(a01, b0, acc1, 0, 0, 0);
        short8 b1  = *(const short8*)(Lb + (size_t)(4 + w4) * 512 + l * 8);
        short8 a10 = *(const short8*)(La + 1024 + (size_t)l * 8);
        short8 a11 = *(const short8*)(La + 1536 + (size_t)l * 8);
        acc0 = __builtin_amdgcn_mfma_f32_16x16x32_bf16(a10, b1, acc0, 0, 0, 0);
        acc1 = __builtin_amdgcn_mfma_f32_16x16x32_bf16(a11, b1, acc1, 0, 0, 0);
    }

    const int c = l & 15, rg = l >> 4;
    const int nl = w4 * 16 + c;
    if (kg == 0) {
#pragma unroll
        for (int mb = 0; mb < 2; ++mb) {
            f32x4 acc = mb ? acc1 : acc0;
#pragma unroll
            for (int rr = 0; rr < 4; ++rr)
                red[mb * 16 + rg * 4 + rr][nl] = acc[rr];
        }
    }
    __syncthreads();
    if (kg == 1) {
        float bv = bias[nt * 64 + nl];
#pragma unroll
        for (int mb = 0; mb < 2; ++mb) {
            f32x4 acc = mb ? acc1 : acc0;
#pragma unroll
            for (int rr = 0; rr < 4; ++rr) {
                int m = mb * 16 + rg * 4 + rr;
                C[(size_t)(mt * 32 + m) * 1024 + nt * 64 + nl] =
                    red[m][nl] + acc[rr] + bv;
            }
        }
    }
}

// ---------------------------------------------------------------------------
extern "C" void kernel_launch(void* const* d_in, const int* in_sizes, int n_in,
                              void* d_out, int out_size, void* d_ws, size_t ws_size,
                              hipStream_t stream)
{
    const float* x        = (const float*)d_in[0];
    const float* cached_k = (const float*)d_in[1];
    const float* cached_v = (const float*)d_in[2];
    const float* w_attn   = (const float*)d_in[3];
    const float* b_attn   = (const float*)d_in[4];
    const float* w_proj   = (const float*)d_in[5];
    const float* b_proj   = (const float*)d_in[6];
    const float* k_conv   = (const float*)d_in[7];
    const float* v_conv   = (const float*)d_in[8];
    const float* ln_k_g   = (const float*)d_in[9];
    const float* ln_k_b   = (const float*)d_in[10];
    const float* ln_v_g   = (const float*)d_in[11];
    const float* ln_v_b   = (const float*)d_in[12];

    ushort* xp   = (ushort*)d_ws;          // 524288 u16
    ushort* wq   = xp + 524288;            // 1048576 u16
    ushort* wp   = wq + 1048576;           // 1048576 u16
    ushort* yp   = wp + 1048576;           // 524288 u16
    ushort* ckf  = yp + 524288;            // 524288 u16
    ushort* cvtf = ckf + 524288;           // 524288 u16
    float* out   = (float*)d_out;

    prep_kernel<<<512, 256, 0, stream>>>(cached_k, cached_v, k_conv, v_conv,
                                         ln_k_g, ln_k_b, ln_v_g, ln_v_b,
                                         x, w_attn, w_proj, ckf, cvtf, xp, wq, wp);
    attn_kernel<<<256, 512, 0, stream>>>(ckf, cvtf, b_attn, xp, wq, yp);
    gemm2_kernel<<<256, 512, 0, stream>>>(yp, wp, b_proj, out);
}

// Round 9
// 26.880 us; speedup vs baseline: 5.2805x; 1.0504x over previous
//
#include <hip/hip_runtime.h>
#include <math.h>

#define NH 16
#define LCACHE 4096

typedef __attribute__((ext_vector_type(8))) short short8;
typedef __attribute__((ext_vector_type(8))) unsigned short ushort8;
typedef __attribute__((ext_vector_type(4))) float f32x4;

__device__ __forceinline__ unsigned short f2bf(float f) {
    unsigned int u = __float_as_uint(f);
    u = (u + 0x7fffu + ((u >> 16) & 1u)) >> 16;   // RNE
    return (unsigned short)u;
}

// ---------------------------------------------------------------------------
// K1 prep: 512 blocks x 256 thr.  Per block: compress unit (loads issued
// FIRST — they head the critical path) + wpack unit (loads second, land under
// compress compute).  xpack on bid<64.
//   compress: bh=bid>>2, T=(bid>>1)&1, half=bid&1 -> 32 rows conv+LN ->
//             bf16 MFMA A-frags (ck: [m=key,k=d]; cv transposed: [m=d,k=key]).
//   wpack:    bid<256 -> wq (w_attn[:, :1024]); else wp (w_proj), unit (nt,kt).
// ---------------------------------------------------------------------------
__global__ __launch_bounds__(256)
void prep_kernel(const float* __restrict__ cached_k, const float* __restrict__ cached_v,
                 const float* __restrict__ kcw, const float* __restrict__ vcw,
                 const float* __restrict__ lkg, const float* __restrict__ lkb,
                 const float* __restrict__ lvg, const float* __restrict__ lvb,
                 const float* __restrict__ x, const float* __restrict__ w_attn,
                 const float* __restrict__ w_proj,
                 ushort* __restrict__ ckf, ushort* __restrict__ cvtf,
                 ushort* __restrict__ xp, ushort* __restrict__ wq,
                 ushort* __restrict__ wp)
{
    __shared__ float Wt[64][65];
    const int bid = blockIdx.x, tid = threadIdx.x;
    const int w = tid >> 6, l = tid & 63;

    // ---- compress tap loads FIRST (critical path) ----
    const int bh = bid >> 2, sub = bid & 3;
    const int T = sub >> 1, half = sub & 1;
    const float* S = (T ? cached_v : cached_k) + (size_t)bh * (LCACHE * 64);
    float tap[8][4];
#pragma unroll
    for (int rq = 0; rq < 8; ++rq) {
        int key = half * 32 + w * 8 + rq;
        const float* p = S + (size_t)key * 256 + l;
        tap[rq][0] = p[0]; tap[rq][1] = p[64]; tap[rq][2] = p[128]; tap[rq][3] = p[192];
    }

    // ---- wpack staging loads second (land under compress compute) ----
    const int isP = (bid >= 256);
    const int g2  = bid & 255;
    const int ntw = g2 >> 4, ktw = g2 & 15;
    const float* W = isP ? w_proj : w_attn;
    const int ldw  = isP ? 1024 : 3072;
    ushort* D      = isP ? wp : wq;
    float wreg[16];
#pragma unroll
    for (int rep = 0; rep < 16; ++rep) {
        int lin = rep * 256 + tid;
        int kr = lin >> 6, nn = lin & 63;
        wreg[rep] = W[(size_t)(ktw * 64 + kr) * ldw + ntw * 64 + nn];
    }

    // ---- compress compute: conv taps -> LN (batched shuffle trees) -> scatter
    {
        const float* cwp = T ? vcw : kcw;
        float4 w4v = *(const float4*)(cwp + l * 4);
        float g = (T ? lvg : lkg)[l], bb = (T ? lvb : lkb)[l];
        ushort* dstf = (T ? cvtf : ckf) + (size_t)bh * 4096;
#pragma unroll
        for (int it = 0; it < 2; ++it) {
            float av[4];
#pragma unroll
            for (int q = 0; q < 4; ++q) {
                int rq = it * 4 + q;
                float acc = tap[rq][0] * w4v.x;
                acc = fmaf(tap[rq][1], w4v.y, acc);
                acc = fmaf(tap[rq][2], w4v.z, acc);
                acc = fmaf(tap[rq][3], w4v.w, acc);
                av[q] = acc;
            }
            float s1[4], s2[4];
#pragma unroll
            for (int q = 0; q < 4; ++q) { s1[q] = av[q]; s2[q] = av[q] * av[q]; }
#pragma unroll
            for (int o = 32; o; o >>= 1) {
#pragma unroll
                for (int q = 0; q < 4; ++q) {
                    s1[q] += __shfl_xor(s1[q], o);
                    s2[q] += __shfl_xor(s2[q], o);
                }
            }
#pragma unroll
            for (int q = 0; q < 4; ++q) {
                int key = half * 32 + w * 8 + it * 4 + q;
                float mu  = s1[q] * 0.015625f;
                float var = s2[q] * 0.015625f - mu * mu;
                float outv = (av[q] - mu) * rsqrtf(var + 1e-5f) * g + bb;
                const int d = l;
                int off;
                if (T) // cv^T frag: (m=d, k=key)
                    off = ((d >> 4) * 2 + (key >> 5)) * 512
                        + ((key >> 3) & 3) * 128 + (d & 15) * 8 + (key & 7);
                else   // ck frag: (m=key, k=d)
                    off = ((key >> 4) * 2 + (d >> 5)) * 512
                        + ((d >> 3) & 3) * 128 + (key & 15) * 8 + (d & 7);
                dstf[off] = f2bf(outv);
            }
        }
    }

    // ---- wpack: regs -> LDS, transpose-pack 8 frags ----
    {
#pragma unroll
        for (int rep = 0; rep < 16; ++rep) {
            int lin = rep * 256 + tid;
            Wt[lin >> 6][lin & 63] = wreg[rep];
        }
        __syncthreads();
        int r = l & 15, kg8 = l >> 4;
#pragma unroll
        for (int e = 0; e < 2; ++e) {
            int bi = w + e * 4;
            int kb = bi >> 2, nb = bi & 3;
            ushort8 o;
#pragma unroll
            for (int j = 0; j < 8; ++j)
                o[j] = f2bf(Wt[kb * 32 + kg8 * 8 + j][nb * 16 + r]);
            size_t f_lin = (size_t)(ntw * 16 + ktw) * 8 + bi;
            *(ushort8*)(D + f_lin * 512 + l * 8) = o;
        }
    }

    // ---- xpack ----
    if (bid < 64) {
        int r = l & 15, kg8 = l >> 4;
#pragma unroll
        for (int i = 0; i < 4; ++i) {
            int f = bid * 16 + w * 4 + i;
            int mt = f >> 6, kt = (f >> 2) & 15, fi = f & 3;
            int kb = fi >> 1, mb = fi & 1;
            int m  = mt * 32 + mb * 16 + r;
            int k0 = kt * 64 + kb * 32 + kg8 * 8;
            const float* s = x + (size_t)m * 1024 + k0;
            ushort8 o;
#pragma unroll
            for (int j = 0; j < 8; ++j) o[j] = f2bf(s[j]);
            *(ushort8*)(xp + (size_t)f * 512 + l * 8) = o;
        }
    }
}

// ---------------------------------------------------------------------------
// K2: per (b,h,half).  Reg-direct q-GEMM (barrier-free; wave = kg x nb, full
// unroll; frag loads lane-linear from packed xp/wq) | split-K LDS reduce |
// MFMA attention (S^T = mfma(ck,q), in-reg softmax, P_lds XOR-swizzled,
// O^T = mfma(cv^T,P)) | yp frag scatter.  ck/cv frag loads hoisted to top.
// ---------------------------------------------------------------------------
__global__ __launch_bounds__(512, 2)
void attn_kernel(const ushort* __restrict__ ckf, const ushort* __restrict__ cvtf,
                 const float* __restrict__ b_attn,
                 const ushort* __restrict__ xp, const ushort* __restrict__ wq,
                 ushort* __restrict__ yp)
{
    __shared__ __align__(16) float qs[32][68];
    __shared__ __align__(16) ushort P_lds[32 * 64];

    const int bid = blockIdx.x;
    const int h    = ((bid & 7) << 1) | ((bid >> 3) & 1);   // same h -> same XCD
    const int rem  = bid >> 4;
    const int b    = rem >> 1;
    const int half = rem & 1;
    const int mtA  = b * 2 + half;

    const int tid = threadIdx.x;
    const int w = tid >> 6, l = tid & 63;
    const int kg = w >> 2, w4 = w & 3;
    const int c = l & 15, rg = l >> 4;
    const int g = w & 1, dup = w >> 1;

    // hoisted ck/cv fragment loads (land under the q-GEMM)
    const ushort* ckb = ckf + (size_t)(b * NH + h) * 4096;
    const ushort* cvb = cvtf + (size_t)(b * NH + h) * 4096;
    short8 akf[4][2];
#pragma unroll
    for (int mf = 0; mf < 4; ++mf)
#pragma unroll
        for (int kf = 0; kf < 2; ++kf)
            akf[mf][kf] = *(const short8*)(ckb + (mf * 2 + kf) * 512 + l * 8);
    short8 avf[2];
#pragma unroll
    for (int kf = 0; kf < 2; ++kf)
        avf[kf] = *(const short8*)(cvb + (dup * 2 + kf) * 512 + l * 8);

    // ---- reg-direct q-GEMM: wave (kg, w4) owns nb=w4, both mb, K-half kg ----
    const ushort* ab = xp + (size_t)mtA * 32768;
    const ushort* bb = wq + (size_t)h * 65536;
    f32x4 acc0 = {0.f,0.f,0.f,0.f}, acc1 = {0.f,0.f,0.f,0.f};
#pragma unroll
    for (int s = 0; s < 8; ++s) {
        const int kt = kg * 8 + s;
        const ushort* A = ab + kt * 2048;
        const ushort* B = bb + kt * 4096;
        short8 a00 = *(const short8*)(A + l * 8);                  // kb0 mb0
        short8 a01 = *(const short8*)(A + 512 + l * 8);            // kb0 mb1
        short8 a10 = *(const short8*)(A + 1024 + l * 8);           // kb1 mb0
        short8 a11 = *(const short8*)(A + 1536 + l * 8);           // kb1 mb1
        short8 b0  = *(const short8*)(B + (size_t)w4 * 512 + l * 8);        // kb0
        short8 b1  = *(const short8*)(B + (size_t)(4 + w4) * 512 + l * 8);  // kb1
        acc0 = __builtin_amdgcn_mfma_f32_16x16x32_bf16(a00, b0, acc0, 0, 0, 0);
        acc1 = __builtin_amdgcn_mfma_f32_16x16x32_bf16(a01, b0, acc1, 0, 0, 0);
        acc0 = __builtin_amdgcn_mfma_f32_16x16x32_bf16(a10, b1, acc0, 0, 0, 0);
        acc1 = __builtin_amdgcn_mfma_f32_16x16x32_bf16(a11, b1, acc1, 0, 0, 0);
    }

    // split-K reduce -> qs (group1 adds bias + softmax scale)
    {
        const int n = w4 * 16 + c;
        if (kg == 0) {
#pragma unroll
            for (int mb = 0; mb < 2; ++mb) {
                f32x4 acc = mb ? acc1 : acc0;
#pragma unroll
                for (int rr = 0; rr < 4; ++rr)
                    qs[mb * 16 + rg * 4 + rr][n] = acc[rr];
            }
        }
        __syncthreads();
        if (kg == 1) {
            float bv = b_attn[h * 64 + n];
#pragma unroll
            for (int mb = 0; mb < 2; ++mb) {
                f32x4 acc = mb ? acc1 : acc0;
#pragma unroll
                for (int rr = 0; rr < 4; ++rr) {
                    int m = mb * 16 + rg * 4 + rr;
                    qs[m][n] = (qs[m][n] + acc[rr] + bv) * 0.125f;
                }
            }
        }
        __syncthreads();
    }

    // ===== MFMA attention =====
    short8 qb[2];
#pragma unroll
    for (int kf = 0; kf < 2; ++kf) {
        int row = 16 * g + c;
        int d0  = 32 * kf + 8 * rg;
        float4 v0 = *(const float4*)&qs[row][d0];
        float4 v1 = *(const float4*)&qs[row][d0 + 4];
        ushort8 t;
        t[0] = f2bf(v0.x); t[1] = f2bf(v0.y); t[2] = f2bf(v0.z); t[3] = f2bf(v0.w);
        t[4] = f2bf(v1.x); t[5] = f2bf(v1.y); t[6] = f2bf(v1.z); t[7] = f2bf(v1.w);
        qb[kf] = (short8)t;
    }

    f32x4 sacc[4];
#pragma unroll
    for (int mf = 0; mf < 4; ++mf) { sacc[mf][0]=0.f; sacc[mf][1]=0.f; sacc[mf][2]=0.f; sacc[mf][3]=0.f; }
#pragma unroll
    for (int mf = 0; mf < 4; ++mf) {
        sacc[mf] = __builtin_amdgcn_mfma_f32_16x16x32_bf16(akf[mf][0], qb[0], sacc[mf], 0, 0, 0);
        sacc[mf] = __builtin_amdgcn_mfma_f32_16x16x32_bf16(akf[mf][1], qb[1], sacc[mf], 0, 0, 0);
    }

    // softmax: lane holds 16 key-scores for query gq
    const int gq = half * 32 + 16 * g + c;
    float pv[4][4];
    float mx = -3.0e38f;
#pragma unroll
    for (int mf = 0; mf < 4; ++mf)
#pragma unroll
        for (int rr = 0; rr < 4; ++rr) {
            int kidx = 16 * mf + 4 * rg + rr;
            float sc = (kidx <= gq) ? sacc[mf][rr] : -3.0e38f;
            pv[mf][rr] = sc;
            mx = fmaxf(mx, sc);
        }
    mx = fmaxf(mx, __shfl_xor(mx, 16));
    mx = fmaxf(mx, __shfl_xor(mx, 32));
    float sum = 0.f;
#pragma unroll
    for (int mf = 0; mf < 4; ++mf)
#pragma unroll
        for (int rr = 0; rr < 4; ++rr) {
            int kidx = 16 * mf + 4 * rg + rr;
            float e = (kidx <= gq) ? __expf(pv[mf][rr] - mx) : 0.f;
            pv[mf][rr] = e;
            sum += e;
        }
    sum += __shfl_xor(sum, 16);
    sum += __shfl_xor(sum, 32);
    float inv = 1.0f / sum;

    if (dup == 0) {
        int q = 16 * g + c;
        int swz = (q & 7) << 3;
#pragma unroll
        for (int mf = 0; mf < 4; ++mf)
#pragma unroll
            for (int rr = 0; rr < 4; ++rr) {
                int kidx = 16 * mf + 4 * rg + rr;
                P_lds[q * 64 + (kidx ^ swz)] = f2bf(pv[mf][rr] * inv);
            }
    }
    __syncthreads();

    // PV: O^T = mfma(cv^T, P)
    short8 pb[2];
#pragma unroll
    for (int kf = 0; kf < 2; ++kf) {
        int q = 16 * g + c;
        int key0 = 32 * kf + 8 * rg;
        pb[kf] = *(const short8*)&P_lds[q * 64 + (key0 ^ ((q & 7) << 3))];
    }
    f32x4 oacc = {0.f, 0.f, 0.f, 0.f};
    oacc = __builtin_amdgcn_mfma_f32_16x16x32_bf16(avf[0], pb[0], oacc, 0, 0, 0);
    oacc = __builtin_amdgcn_mfma_f32_16x16x32_bf16(avf[1], pb[1], oacc, 0, 0, 0);

    // yp scatter: row i = 16g + c, col d = 16*dup + 4*rg + rr (within head h)
#pragma unroll
    for (int rr = 0; rr < 4; ++rr) {
        int d  = 16 * dup + 4 * rg + rr;
        int kb = d >> 5, ke = d & 31;
        int l2 = ((ke >> 3) << 4) | c;
        int j2 = ke & 7;
        size_t off = (size_t)mtA * 32768 + (size_t)h * 2048
                   + (size_t)(kb * 2 + g) * 512 + (size_t)l2 * 8 + j2;
        yp[off] = f2bf(oacc[rr]);
    }
}

// ---------------------------------------------------------------------------
// K3: out = y @ w_proj + b_proj.  Reg-direct (barrier-free), split-K over
// 8 waves (kg x nb=w4), LDS reduce + bias.  XCD-swizzled nt.
// ---------------------------------------------------------------------------
__global__ __launch_bounds__(512, 2)
void gemm2_kernel(const ushort* __restrict__ Ap, const ushort* __restrict__ Bp,
                  const float* __restrict__ bias, float* __restrict__ C)
{
    __shared__ float red[32][68];

    const int bid = blockIdx.x;
    const int nt = ((bid & 7) << 1) | ((bid >> 3) & 1);
    const int mt = bid >> 4;
    const int tid = threadIdx.x;
    const int w = tid >> 6, l = tid & 63;
    const int kg = w >> 2, w4 = w & 3;
    const int c = l & 15, rg = l >> 4;

    const ushort* ab = Ap + (size_t)mt * 32768;
    const ushort* bb = Bp + (size_t)nt * 65536;
    f32x4 acc0 = {0.f,0.f,0.f,0.f}, acc1 = {0.f,0.f,0.f,0.f};
#pragma unroll
    for (int s = 0; s < 8; ++s) {
        const int kt = kg * 8 + s;
        const ushort* A = ab + kt * 2048;
        const ushort* B = bb + kt * 4096;
        short8 a00 = *(const short8*)(A + l * 8);
        short8 a01 = *(const short8*)(A + 512 + l * 8);
        short8 a10 = *(const short8*)(A + 1024 + l * 8);
        short8 a11 = *(const short8*)(A + 1536 + l * 8);
        short8 b0  = *(const short8*)(B + (size_t)w4 * 512 + l * 8);
        short8 b1  = *(const short8*)(B + (size_t)(4 + w4) * 512 + l * 8);
        acc0 = __builtin_amdgcn_mfma_f32_16x16x32_bf16(a00, b0, acc0, 0, 0, 0);
        acc1 = __builtin_amdgcn_mfma_f32_16x16x32_bf16(a01, b0, acc1, 0, 0, 0);
        acc0 = __builtin_amdgcn_mfma_f32_16x16x32_bf16(a10, b1, acc0, 0, 0, 0);
        acc1 = __builtin_amdgcn_mfma_f32_16x16x32_bf16(a11, b1, acc1, 0, 0, 0);
    }

    const int nl = w4 * 16 + c;
    if (kg == 0) {
#pragma unroll
        for (int mb = 0; mb < 2; ++mb) {
            f32x4 acc = mb ? acc1 : acc0;
#pragma unroll
            for (int rr = 0; rr < 4; ++rr)
                red[mb * 16 + rg * 4 + rr][nl] = acc[rr];
        }
    }
    __syncthreads();
    if (kg == 1) {
        float bv = bias[nt * 64 + nl];
#pragma unroll
        for (int mb = 0; mb < 2; ++mb) {
            f32x4 acc = mb ? acc1 : acc0;
#pragma unroll
            for (int rr = 0; rr < 4; ++rr) {
                int m = mb * 16 + rg * 4 + rr;
                C[(size_t)(mt * 32 + m) * 1024 + nt * 64 + nl] =
                    red[m][nl] + acc[rr] + bv;
            }
        }
    }
}

// ---------------------------------------------------------------------------
extern "C" void kernel_launch(void* const* d_in, const int* in_sizes, int n_in,
                              void* d_out, int out_size, void* d_ws, size_t ws_size,
                              hipStream_t stream)
{
    const float* x        = (const float*)d_in[0];
    const float* cached_k = (const float*)d_in[1];
    const float* cached_v = (const float*)d_in[2];
    const float* w_attn   = (const float*)d_in[3];
    const float* b_attn   = (const float*)d_in[4];
    const float* w_proj   = (const float*)d_in[5];
    const float* b_proj   = (const float*)d_in[6];
    const float* k_conv   = (const float*)d_in[7];
    const float* v_conv   = (const float*)d_in[8];
    const float* ln_k_g   = (const float*)d_in[9];
    const float* ln_k_b   = (const float*)d_in[10];
    const float* ln_v_g   = (const float*)d_in[11];
    const float* ln_v_b   = (const float*)d_in[12];

    ushort* xp   = (ushort*)d_ws;          // 524288 u16
    ushort* wq   = xp + 524288;            // 1048576 u16
    ushort* wp   = wq + 1048576;           // 1048576 u16
    ushort* yp   = wp + 1048576;           // 524288 u16
    ushort* ckf  = yp + 524288;            // 524288 u16
    ushort* cvtf = ckf + 524288;           // 524288 u16
    float* out   = (float*)d_out;

    prep_kernel<<<512, 256, 0, stream>>>(cached_k, cached_v, k_conv, v_conv,
                                         ln_k_g, ln_k_b, ln_v_g, ln_v_b,
                                         x, w_attn, w_proj, ckf, cvtf, xp, wq, wp);
    attn_kernel<<<256, 512, 0, stream>>>(ckf, cvtf, b_attn, xp, wq, yp);
    gemm2_kernel<<<256, 512, 0, stream>>>(yp, wp, b_proj, out);
}